// Round 5
// baseline (263.601 us; speedup 1.0000x reference)
//
#include <hip/hip_runtime.h>

#define NN 384
#define CC 128
#define PP (NN*NN)      // 147456 positions
#define PB 128          // positions per block
#define NB (PP/PB)      // 1152 blocks
#define TPB 512         // 8 waves; each wave owns one 16-row stripe

typedef __attribute__((ext_vector_type(8))) short bf16x8;
typedef __attribute__((ext_vector_type(4))) float f32x4;
typedef __attribute__((ext_vector_type(8))) unsigned short u16x8;

// weight planes in wfrag, 16384 ushorts (32KB) each
#define PL_APH 0
#define PL_AGH 1
#define PL_BPH 2
#define PL_BGH 3
#define PL_APL 4
#define PL_AGL 5
#define PL_BPL 6
#define PL_BGL 7
#define PL_G   8
#define PL_Z   9

__device__ __forceinline__ unsigned short f2bf(float f){
  unsigned u = __float_as_uint(f);
  u += 0x7FFFu + ((u>>16)&1u);          // RNE
  return (unsigned short)(u>>16);
}
__device__ __forceinline__ float bf2f(unsigned h){
  return __uint_as_float(h<<16);
}
__device__ __forceinline__ unsigned pack2(float a, float b){
  return (unsigned)f2bf(a) | ((unsigned)f2bf(b)<<16);
}
__device__ __forceinline__ float sigmoidf_(float x){
  return __fdividef(1.0f, 1.0f + __expf(-x));
}

// ---------------------------------------------------------------------------
// K0: weights -> bf16 hi/lo planes in MFMA-B-fragment order.
// chunk (k0*8+n)*64+l holds W[n*16+(l&15)][k0*32+(l>>4)*8 .. +7].
// ---------------------------------------------------------------------------
__global__ __launch_bounds__(256) void k0_wprep(
    const float* __restrict__ wap, const float* __restrict__ wag,
    const float* __restrict__ wbp, const float* __restrict__ wbg,
    const float* __restrict__ wg,  const float* __restrict__ wz,
    unsigned short* __restrict__ wfrag){
  int tid = blockIdx.x*256 + threadIdx.x;      // 0..20479
  int plane = tid >> 11;                       // 0..9
  int chunk = tid & 2047;
  int mat = (plane < 8) ? (plane & 3) : (plane == 8 ? 4 : 5);
  bool lo = (plane >= 4) && (plane < 8);
  const float* W = (mat==0)?wap:(mat==1)?wag:(mat==2)?wbp:(mat==3)?wbg:(mat==4)?wg:wz;
  int k0 = chunk >> 9, n = (chunk >> 6) & 7, l = chunk & 63;
  int o  = n*16 + (l & 15);
  int kb = k0*32 + ((l>>4)<<3);
  const float* s = W + o*128 + kb;
  u16x8 v;
  #pragma unroll
  for (int e=0;e<8;e++){
    float w = s[e];
    unsigned short h = f2bf(w);
    v[e] = lo ? f2bf(w - bf2f(h)) : h;
  }
  *(u16x8*)(wfrag + (size_t)tid*8) = v;
}

// ---------------------------------------------------------------------------
// Per-stripe MFMA helpers (one 16-row A stripe, 8 n-fragments of output).
// A-frag: row = row0+(l&15), k = k0*32+(l>>4)*8+e.
// D: row = row0+(l>>4)*4+r, col = n*16+(l&15).
// ---------------------------------------------------------------------------
__device__ __forceinline__ void mm_pair3(const bf16x8 aH[4], const bf16x8 aL[4],
    const unsigned short* __restrict__ wpH, const unsigned short* __restrict__ wpL,
    const unsigned short* __restrict__ wgH, const unsigned short* __restrict__ wgL,
    const float* __restrict__ bp, const float* __restrict__ bg, int l,
    f32x4 accp[8], f32x4 accg[8]){
  #pragma unroll
  for (int n=0;n<8;n++){
    float vp = bp[n*16 + (l&15)];
    float vg = bg[n*16 + (l&15)];
    f32x4 ip = {vp,vp,vp,vp}, ig = {vg,vg,vg,vg};
    accp[n]=ip; accg[n]=ig;
  }
  #pragma unroll
  for (int k0=0;k0<4;k0++){
    #pragma unroll
    for (int n=0;n<8;n++){
      int co = ((k0*8+n)*64 + l)*8;
      bf16x8 fpH = *(const bf16x8*)(wpH + co);
      bf16x8 fpL = *(const bf16x8*)(wpL + co);
      bf16x8 fgH = *(const bf16x8*)(wgH + co);
      bf16x8 fgL = *(const bf16x8*)(wgL + co);
      accp[n] = __builtin_amdgcn_mfma_f32_16x16x32_bf16(aH[k0], fpH, accp[n], 0,0,0);
      accp[n] = __builtin_amdgcn_mfma_f32_16x16x32_bf16(aH[k0], fpL, accp[n], 0,0,0);
      accp[n] = __builtin_amdgcn_mfma_f32_16x16x32_bf16(aL[k0], fpH, accp[n], 0,0,0);
      accg[n] = __builtin_amdgcn_mfma_f32_16x16x32_bf16(aH[k0], fgH, accg[n], 0,0,0);
      accg[n] = __builtin_amdgcn_mfma_f32_16x16x32_bf16(aH[k0], fgL, accg[n], 0,0,0);
      accg[n] = __builtin_amdgcn_mfma_f32_16x16x32_bf16(aL[k0], fgH, accg[n], 0,0,0);
    }
  }
}

__device__ __forceinline__ void mm_single(const bf16x8 a[4],
    const unsigned short* __restrict__ wm, const float* __restrict__ bias, int l,
    f32x4 acc[8]){
  #pragma unroll
  for (int n=0;n<8;n++){
    float v = bias[n*16 + (l&15)];
    f32x4 iv = {v,v,v,v};
    acc[n]=iv;
  }
  #pragma unroll
  for (int k0=0;k0<4;k0++){
    #pragma unroll
    for (int n=0;n<8;n++){
      bf16x8 f = *(const bf16x8*)(wm + (((k0*8+n)*64 + l)*8));
      acc[n] = __builtin_amdgcn_mfma_f32_16x16x32_bf16(a[k0], f, acc[n], 0,0,0);
    }
  }
}

// ---------------------------------------------------------------------------
// Fused kernel, per 128-position tile; 8 waves, one 16-row stripe each.
//  P1  zn = LN(z) f32 -> hi/lo bf16 in bufH/bufL (XOR-swizzled)   [barrier]
//  P2  aH/aL fragments (wave-local rows from here on)
//  P3  a = (zn@Wap^T+bap)*sig(zn@Wag^T+bag)*mask   [f32, in regs]
//  P4  b likewise; x = a*b in f32 regs
//  P5  xn = LN(x) in-register (16-lane reduce) -> bufL bf16 (own rows)
//  P6  o = xn@Wz^T+bz ; gv = zn@Wg^T+bg            [barrier]
//  P7  f32 repack of o*sig(gv) over whole 64KB LDS  [barrier] -> float4 stores
// ---------------------------------------------------------------------------
__global__ __launch_bounds__(TPB,2) void k_fused(
    const float* __restrict__ z, const float* __restrict__ mask,
    const float* __restrict__ bap, const float* __restrict__ bag,
    const float* __restrict__ bbp, const float* __restrict__ bbg,
    const float* __restrict__ bgg, const float* __restrict__ bz,
    const float* __restrict__ lniw, const float* __restrict__ lnib,
    const float* __restrict__ lnow, const float* __restrict__ lnob,
    const unsigned short* __restrict__ wfrag,
    float* __restrict__ out){
  __shared__ unsigned char lds[65536];
  unsigned char* bufH = lds;            // zn hi
  unsigned char* bufL = lds + 32768;    // zn lo, later xn
  const int t = threadIdx.x;
  const int pos0 = blockIdx.x * PB;
  const int rowg = t>>5, c4 = (t&31)<<2;

  // ---- P1: LN(z), two-pass var, hi/lo split ----
  {
    float4 lw = *(const float4*)(lniw + c4);
    float4 lb = *(const float4*)(lnib + c4);
    #pragma unroll
    for (int it=0; it<8; ++it){
      int row = it*16 + rowg;
      float4 v = *(const float4*)(z + (size_t)(pos0+row)*CC + c4);
      float s = v.x+v.y+v.z+v.w;
      #pragma unroll
      for (int mm=1; mm<32; mm<<=1) s += __shfl_xor(s,mm);
      float mu = s*(1.0f/128.0f);
      float d0=v.x-mu, d1=v.y-mu, d2=v.z-mu, d3=v.w-mu;
      float ss = d0*d0+d1*d1+d2*d2+d3*d3;
      #pragma unroll
      for (int mm=1; mm<32; mm<<=1) ss += __shfl_xor(ss,mm);
      float rstd = rsqrtf(ss*(1.0f/128.0f) + 1e-5f);
      float n0=d0*rstd*lw.x+lb.x, n1=d1*rstd*lw.y+lb.y;
      float n2=d2*rstd*lw.z+lb.z, n3=d3*rstd*lw.w+lb.w;
      unsigned short h0=f2bf(n0), h1=f2bf(n1), h2=f2bf(n2), h3=f2bf(n3);
      unsigned off = (unsigned)(row*256 + ((c4<<1) ^ ((row&7)<<4)));
      *(uint2*)(bufH + off) = make_uint2((unsigned)h0|((unsigned)h1<<16),
                                         (unsigned)h2|((unsigned)h3<<16));
      *(uint2*)(bufL + off) = make_uint2(pack2(n0-bf2f(h0), n1-bf2f(h1)),
                                         pack2(n2-bf2f(h2), n3-bf2f(h3)));
    }
  }
  __syncthreads();

  const int wv = t>>6, l = t&63;
  const int cb = l&15;            // D col-within-16 / A row-within-16
  const int g4 = (l>>4)<<2;       // D row-quad base
  const int row0 = wv*16;         // this wave's stripe

  // ---- P2: A-fragments (hi and lo) of own stripe ----
  bf16x8 aH[4], aLo[4];
  #pragma unroll
  for (int k0=0;k0<4;k0++){
    int row = row0 + cb;
    unsigned off = (unsigned)(row*256 + ((((l>>4)<<4) + (k0<<6)) ^ ((row&7)<<4)));
    aH[k0]  = *(const bf16x8*)(bufH + off);
    aLo[k0] = *(const bf16x8*)(bufL + off);
  }

  float mk[4];
  #pragma unroll
  for (int r=0;r<4;r++) mk[r] = mask[pos0 + row0 + g4 + r];

  f32x4 accp[8], accg[8];

  // ---- P3: a (f32-grade) ----
  mm_pair3(aH, aLo,
           wfrag + PL_APH*16384, wfrag + PL_APL*16384,
           wfrag + PL_AGH*16384, wfrag + PL_AGL*16384,
           bap, bag, l, accp, accg);
  f32x4 xv[8];
  #pragma unroll
  for (int n=0;n<8;n++)
    #pragma unroll
    for (int r=0;r<4;r++)
      xv[n][r] = accp[n][r]*sigmoidf_(accg[n][r])*mk[r];

  // ---- P4: b ; x = a*b ----
  mm_pair3(aH, aLo,
           wfrag + PL_BPH*16384, wfrag + PL_BPL*16384,
           wfrag + PL_BGH*16384, wfrag + PL_BGL*16384,
           bbp, bbg, l, accp, accg);
  #pragma unroll
  for (int n=0;n<8;n++)
    #pragma unroll
    for (int r=0;r<4;r++)
      xv[n][r] *= accp[n][r]*sigmoidf_(accg[n][r])*mk[r];

  // ---- P5: LN(x) in-register; each row lives on one 16-lane group ----
  {
    float lw8[8], lb8[8];
    #pragma unroll
    for (int n=0;n<8;n++){ lw8[n]=lnow[n*16+cb]; lb8[n]=lnob[n*16+cb]; }
    #pragma unroll
    for (int r=0;r<4;r++){
      float s=0.f;
      #pragma unroll
      for (int n=0;n<8;n++) s += xv[n][r];
      #pragma unroll
      for (int mm=1; mm<16; mm<<=1) s += __shfl_xor(s,mm);
      float mu = s*(1.0f/128.0f);
      float ss=0.f;
      #pragma unroll
      for (int n=0;n<8;n++){ float d = xv[n][r]-mu; ss += d*d; }
      #pragma unroll
      for (int mm=1; mm<16; mm<<=1) ss += __shfl_xor(ss,mm);
      float rstd = rsqrtf(ss*(1.0f/128.0f) + 1e-5f);
      int row = row0 + g4 + r;
      #pragma unroll
      for (int n=0;n<8;n++){
        int col = n*16 + cb;
        float v = (xv[n][r]-mu)*rstd*lw8[n]+lb8[n];
        *(unsigned short*)(bufL + row*256 + ((col<<1) ^ ((row&7)<<4))) = f2bf(v);
      }
    }
  }
  // no barrier: P5 wrote only this wave's rows; afr2 reads the same rows

  // ---- P6: o = xn@Wz^T+bz ; gv = zn@Wg^T+bg ----
  bf16x8 a2[4];
  #pragma unroll
  for (int k0=0;k0<4;k0++){
    int row = row0 + cb;
    unsigned off = (unsigned)(row*256 + ((((l>>4)<<4) + (k0<<6)) ^ ((row&7)<<4)));
    a2[k0] = *(const bf16x8*)(bufL + off);
  }
  f32x4 o[8], gv[8];
  mm_single(a2, wfrag + PL_Z*16384, bz,  l, o);
  mm_single(aH, wfrag + PL_G*16384, bgg, l, gv);
  __syncthreads();   // all LDS reads complete before f32 repack overwrites

  // ---- P7: f32 repack over whole 64KB (row stride 512B), then float4 store ----
  #pragma unroll
  for (int r=0;r<4;r++){
    int row = row0 + g4 + r;
    #pragma unroll
    for (int n=0;n<8;n++){
      int col = n*16 + cb;
      *(float*)(lds + row*512 + ((col<<2) ^ ((row&4)<<4))) = o[n][r]*sigmoidf_(gv[n][r]);
    }
  }
  __syncthreads();
  #pragma unroll
  for (int it=0; it<8; ++it){
    int row = it*16 + rowg;
    float4 v = *(const float4*)(lds + row*512 + (((t&31)<<4) ^ ((row&4)<<4)));
    *(float4*)(out + (size_t)(pos0+row)*CC + c4) = v;
  }
}

extern "C" void kernel_launch(void* const* d_in, const int* in_sizes, int n_in,
                              void* d_out, int out_size, void* d_ws, size_t ws_size,
                              hipStream_t stream){
  const float* z     = (const float*)d_in[0];
  const float* mask  = (const float*)d_in[1];
  const float* w_ap  = (const float*)d_in[2];
  const float* b_ap  = (const float*)d_in[3];
  const float* w_bp  = (const float*)d_in[4];
  const float* b_bp  = (const float*)d_in[5];
  const float* w_ag  = (const float*)d_in[6];
  const float* b_ag  = (const float*)d_in[7];
  const float* w_bg  = (const float*)d_in[8];
  const float* b_bg  = (const float*)d_in[9];
  const float* w_g   = (const float*)d_in[10];
  const float* b_g   = (const float*)d_in[11];
  const float* w_z   = (const float*)d_in[12];
  const float* b_z   = (const float*)d_in[13];
  const float* ln_in_w  = (const float*)d_in[14];
  const float* ln_in_b  = (const float*)d_in[15];
  const float* ln_out_w = (const float*)d_in[16];
  const float* ln_out_b = (const float*)d_in[17];

  unsigned short* wfrag = (unsigned short*)d_ws;   // 10 planes * 32KB = 320KB

  k0_wprep<<<80, 256, 0, stream>>>(w_ap, w_ag, w_bp, w_bg, w_g, w_z, wfrag);
  k_fused<<<NB, TPB, 0, stream>>>(z, mask, b_ap, b_ag, b_bp, b_bg, b_g, b_z,
                                  ln_in_w, ln_in_b, ln_out_w, ln_out_b,
                                  wfrag, (float*)d_out);
}

// Round 6
// 194.202 us; speedup vs baseline: 1.3574x; 1.3574x over previous
//
#include <hip/hip_runtime.h>

#define NN 384
#define CC 128
#define PP (NN*NN)      // 147456 positions
#define PB 128          // positions per block
#define NB (PP/PB)      // 1152 blocks
#define TPB 512         // 8 waves; each wave owns one 16-row stripe

typedef __attribute__((ext_vector_type(8))) short bf16x8;
typedef __attribute__((ext_vector_type(4))) float f32x4;
typedef __attribute__((ext_vector_type(8))) unsigned short u16x8;

// weight planes in wfrag, 16384 ushorts (32KB) each
#define PL_APH 0
#define PL_AGH 1
#define PL_BPH 2
#define PL_BGH 3
#define PL_APL 4
#define PL_AGL 5
#define PL_BPL 6
#define PL_BGL 7
#define PL_G   8
#define PL_Z   9

__device__ __forceinline__ unsigned short f2bf(float f){
  unsigned u = __float_as_uint(f);
  u += 0x7FFFu + ((u>>16)&1u);          // RNE
  return (unsigned short)(u>>16);
}
__device__ __forceinline__ float bf2f(unsigned h){
  return __uint_as_float(h<<16);
}
__device__ __forceinline__ unsigned pack2(float a, float b){
  return (unsigned)f2bf(a) | ((unsigned)f2bf(b)<<16);
}
__device__ __forceinline__ float sigmoidf_(float x){
  return __fdividef(1.0f, 1.0f + __expf(-x));
}

// ---------------------------------------------------------------------------
// K0: weights -> bf16 hi/lo planes in MFMA-B-fragment order.
// chunk (k0*8+n)*64+l holds W[n*16+(l&15)][k0*32+(l>>4)*8 .. +7].
// ---------------------------------------------------------------------------
__global__ __launch_bounds__(256) void k0_wprep(
    const float* __restrict__ wap, const float* __restrict__ wag,
    const float* __restrict__ wbp, const float* __restrict__ wbg,
    const float* __restrict__ wg,  const float* __restrict__ wz,
    unsigned short* __restrict__ wfrag){
  int tid = blockIdx.x*256 + threadIdx.x;      // 0..20479
  int plane = tid >> 11;                       // 0..9
  int chunk = tid & 2047;
  int mat = (plane < 8) ? (plane & 3) : (plane == 8 ? 4 : 5);
  bool lo = (plane >= 4) && (plane < 8);
  const float* W = (mat==0)?wap:(mat==1)?wag:(mat==2)?wbp:(mat==3)?wbg:(mat==4)?wg:wz;
  int k0 = chunk >> 9, n = (chunk >> 6) & 7, l = chunk & 63;
  int o  = n*16 + (l & 15);
  int kb = k0*32 + ((l>>4)<<3);
  const float* s = W + o*128 + kb;
  u16x8 v;
  #pragma unroll
  for (int e=0;e<8;e++){
    float w = s[e];
    unsigned short h = f2bf(w);
    v[e] = lo ? f2bf(w - bf2f(h)) : h;
  }
  *(u16x8*)(wfrag + (size_t)tid*8) = v;
}

// ---------------------------------------------------------------------------
// Stage two 32KB planes into LDS (reg-staged; 64B per thread per plane).
// ---------------------------------------------------------------------------
__device__ __forceinline__ void stage2(const unsigned short* __restrict__ g0,
    const unsigned short* __restrict__ g1, unsigned char* wlds, int t){
  #pragma unroll
  for (int i=0;i<4;i++){
    *(uint4*)(wlds + i*8192 + t*16) =
        *(const uint4*)((const unsigned char*)g0 + i*8192 + t*16);
    *(uint4*)(wlds + 32768 + i*8192 + t*16) =
        *(const uint4*)((const unsigned char*)g1 + i*8192 + t*16);
  }
}

// ---------------------------------------------------------------------------
// MFMA passes over LDS-staged planes. A-frag: row=row0+(l&15), k=k0*32+(l>>4)*8+e.
// D: row=row0+(l>>4)*4+r, col=n*16+(l&15).
// hi pass: acc += (aH+aL)·wH as two MFMAs; lo pass: acc += aH·wL.
// ---------------------------------------------------------------------------
__device__ __forceinline__ void pass_hi(const bf16x8 aH[4], const bf16x8 aL[4],
    const unsigned char* w0, const unsigned char* w1, int l,
    f32x4 accp[8], f32x4 accg[8]){
  #pragma unroll
  for (int k0=0;k0<4;k0++){
    #pragma unroll
    for (int n=0;n<8;n++){
      int co = ((k0*8+n)*64 + l)*16;
      bf16x8 fp = *(const bf16x8*)(w0 + co);
      bf16x8 fg = *(const bf16x8*)(w1 + co);
      accp[n] = __builtin_amdgcn_mfma_f32_16x16x32_bf16(aH[k0], fp, accp[n], 0,0,0);
      accp[n] = __builtin_amdgcn_mfma_f32_16x16x32_bf16(aL[k0], fp, accp[n], 0,0,0);
      accg[n] = __builtin_amdgcn_mfma_f32_16x16x32_bf16(aH[k0], fg, accg[n], 0,0,0);
      accg[n] = __builtin_amdgcn_mfma_f32_16x16x32_bf16(aL[k0], fg, accg[n], 0,0,0);
    }
  }
}

__device__ __forceinline__ void pass_lo(const bf16x8 aH[4],
    const unsigned char* w0, const unsigned char* w1, int l,
    f32x4 accp[8], f32x4 accg[8]){
  #pragma unroll
  for (int k0=0;k0<4;k0++){
    #pragma unroll
    for (int n=0;n<8;n++){
      int co = ((k0*8+n)*64 + l)*16;
      bf16x8 fp = *(const bf16x8*)(w0 + co);
      bf16x8 fg = *(const bf16x8*)(w1 + co);
      accp[n] = __builtin_amdgcn_mfma_f32_16x16x32_bf16(aH[k0], fp, accp[n], 0,0,0);
      accg[n] = __builtin_amdgcn_mfma_f32_16x16x32_bf16(aH[k0], fg, accg[n], 0,0,0);
    }
  }
}

__device__ __forceinline__ void pass_single(const bf16x8 a[4],
    const unsigned char* w, int l, f32x4 acc[8]){
  #pragma unroll
  for (int k0=0;k0<4;k0++){
    #pragma unroll
    for (int n=0;n<8;n++){
      bf16x8 f = *(const bf16x8*)(w + ((k0*8+n)*64 + l)*16);
      acc[n] = __builtin_amdgcn_mfma_f32_16x16x32_bf16(a[k0], f, acc[n], 0,0,0);
    }
  }
}

__device__ __forceinline__ void bias_init(const float* __restrict__ b, int l, f32x4 acc[8]){
  #pragma unroll
  for (int n=0;n<8;n++){
    float v = b[n*16 + (l&15)];
    f32x4 iv = {v,v,v,v};
    acc[n]=iv;
  }
}

// ---------------------------------------------------------------------------
// Fused kernel, per 128-position tile; 8 waves, one 16-row stripe each.
// LDS: [bufH 32K][bufL 32K][wlds 64K = two 32K plane slots]
// ---------------------------------------------------------------------------
__global__ __launch_bounds__(TPB,1) void k_fused(
    const float* __restrict__ z, const float* __restrict__ mask,
    const float* __restrict__ bap, const float* __restrict__ bag,
    const float* __restrict__ bbp, const float* __restrict__ bbg,
    const float* __restrict__ bgg, const float* __restrict__ bz,
    const float* __restrict__ lniw, const float* __restrict__ lnib,
    const float* __restrict__ lnow, const float* __restrict__ lnob,
    const unsigned short* __restrict__ wfrag,
    float* __restrict__ out){
  __shared__ unsigned char lds[131072];
  unsigned char* bufH = lds;            // zn hi
  unsigned char* bufL = lds + 32768;    // zn lo, later xn
  unsigned char* wlds = lds + 65536;    // weight slots / final f32 repack
  const int t = threadIdx.x;
  const int pos0 = blockIdx.x * PB;
  const int rowg = t>>5, c4 = (t&31)<<2;

  // ---- stage a-hi planes (overlaps with P1) ----
  stage2(wfrag + PL_APH*16384, wfrag + PL_AGH*16384, wlds, t);

  // ---- P1: LN(z), two-pass var, hi/lo split ----
  {
    float4 lw = *(const float4*)(lniw + c4);
    float4 lb = *(const float4*)(lnib + c4);
    #pragma unroll
    for (int it=0; it<8; ++it){
      int row = it*16 + rowg;
      float4 v = *(const float4*)(z + (size_t)(pos0+row)*CC + c4);
      float s = v.x+v.y+v.z+v.w;
      #pragma unroll
      for (int mm=1; mm<32; mm<<=1) s += __shfl_xor(s,mm);
      float mu = s*(1.0f/128.0f);
      float d0=v.x-mu, d1=v.y-mu, d2=v.z-mu, d3=v.w-mu;
      float ss = d0*d0+d1*d1+d2*d2+d3*d3;
      #pragma unroll
      for (int mm=1; mm<32; mm<<=1) ss += __shfl_xor(ss,mm);
      float rstd = rsqrtf(ss*(1.0f/128.0f) + 1e-5f);
      float n0=d0*rstd*lw.x+lb.x, n1=d1*rstd*lw.y+lb.y;
      float n2=d2*rstd*lw.z+lb.z, n3=d3*rstd*lw.w+lb.w;
      unsigned short h0=f2bf(n0), h1=f2bf(n1), h2=f2bf(n2), h3=f2bf(n3);
      unsigned off = (unsigned)(row*256 + ((c4<<1) ^ ((row&7)<<4)));
      *(uint2*)(bufH + off) = make_uint2((unsigned)h0|((unsigned)h1<<16),
                                         (unsigned)h2|((unsigned)h3<<16));
      *(uint2*)(bufL + off) = make_uint2(pack2(n0-bf2f(h0), n1-bf2f(h1)),
                                         pack2(n2-bf2f(h2), n3-bf2f(h3)));
    }
  }
  __syncthreads();

  const int wv = t>>6, l = t&63;
  const int cb = l&15;            // D col-within-16 / A row-within-16
  const int g4 = (l>>4)<<2;       // D row-quad base
  const int row0 = wv*16;         // this wave's stripe

  // ---- P2: A-fragments (hi and lo) of own stripe ----
  bf16x8 aH[4], aLo[4];
  #pragma unroll
  for (int k0=0;k0<4;k0++){
    int row = row0 + cb;
    unsigned off = (unsigned)(row*256 + ((((l>>4)<<4) + (k0<<6)) ^ ((row&7)<<4)));
    aH[k0]  = *(const bf16x8*)(bufH + off);
    aLo[k0] = *(const bf16x8*)(bufL + off);
  }

  float mk[4];
  #pragma unroll
  for (int r=0;r<4;r++) mk[r] = mask[pos0 + row0 + g4 + r];

  f32x4 accp[8], accg[8], xv[8];

  // ---- P3: a (f32-grade via hi/lo passes) ----
  bias_init(bap, l, accp);
  bias_init(bag, l, accg);
  pass_hi(aH, aLo, wlds, wlds+32768, l, accp, accg);
  __syncthreads();
  stage2(wfrag + PL_APL*16384, wfrag + PL_AGL*16384, wlds, t);
  __syncthreads();
  pass_lo(aH, wlds, wlds+32768, l, accp, accg);
  #pragma unroll
  for (int n=0;n<8;n++)
    #pragma unroll
    for (int r=0;r<4;r++)
      xv[n][r] = accp[n][r]*sigmoidf_(accg[n][r])*mk[r];
  __syncthreads();
  stage2(wfrag + PL_BPH*16384, wfrag + PL_BGH*16384, wlds, t);
  __syncthreads();

  // ---- P4: b ; x = a*b ----
  bias_init(bbp, l, accp);
  bias_init(bbg, l, accg);
  pass_hi(aH, aLo, wlds, wlds+32768, l, accp, accg);
  __syncthreads();
  stage2(wfrag + PL_BPL*16384, wfrag + PL_BGL*16384, wlds, t);
  __syncthreads();
  pass_lo(aH, wlds, wlds+32768, l, accp, accg);
  #pragma unroll
  for (int n=0;n<8;n++)
    #pragma unroll
    for (int r=0;r<4;r++)
      xv[n][r] *= accp[n][r]*sigmoidf_(accg[n][r])*mk[r];
  __syncthreads();
  stage2(wfrag + PL_G*16384, wfrag + PL_Z*16384, wlds, t);

  // ---- P5: LN(x) in-register (overlaps G/Z staging); writes own bufL rows ----
  {
    float lw8[8], lb8[8];
    #pragma unroll
    for (int n=0;n<8;n++){ lw8[n]=lnow[n*16+cb]; lb8[n]=lnob[n*16+cb]; }
    #pragma unroll
    for (int r=0;r<4;r++){
      float s=0.f;
      #pragma unroll
      for (int n=0;n<8;n++) s += xv[n][r];
      #pragma unroll
      for (int mm=1; mm<16; mm<<=1) s += __shfl_xor(s,mm);
      float mu = s*(1.0f/128.0f);
      float ss=0.f;
      #pragma unroll
      for (int n=0;n<8;n++){ float d = xv[n][r]-mu; ss += d*d; }
      #pragma unroll
      for (int mm=1; mm<16; mm<<=1) ss += __shfl_xor(ss,mm);
      float rstd = rsqrtf(ss*(1.0f/128.0f) + 1e-5f);
      int row = row0 + g4 + r;
      #pragma unroll
      for (int n=0;n<8;n++){
        int col = n*16 + cb;
        float v = (xv[n][r]-mu)*rstd*lw8[n]+lb8[n];
        *(unsigned short*)(bufL + row*256 + ((col<<1) ^ ((row&7)<<4))) = f2bf(v);
      }
    }
  }
  __syncthreads();

  // ---- P6: o = xn@Wz^T+bz ; gv = zn@Wg^T+bg ----
  bf16x8 a2[4];
  #pragma unroll
  for (int k0=0;k0<4;k0++){
    int row = row0 + cb;
    unsigned off = (unsigned)(row*256 + ((((l>>4)<<4) + (k0<<6)) ^ ((row&7)<<4)));
    a2[k0] = *(const bf16x8*)(bufL + off);
  }
  f32x4 o[8], gv[8];
  bias_init(bz,  l, o);
  bias_init(bgg, l, gv);
  pass_single(a2, wlds+32768, l, o);   // Z plane
  pass_single(aH, wlds,       l, gv);  // G plane
  __syncthreads();   // all LDS reads complete before f32 repack overwrites wlds

  // ---- P7: f32 repack into wlds (128 rows x 512B), then float4 store ----
  #pragma unroll
  for (int r=0;r<4;r++){
    int row = row0 + g4 + r;
    #pragma unroll
    for (int n=0;n<8;n++){
      int col = n*16 + cb;
      *(float*)(wlds + row*512 + ((col<<2) ^ ((row&4)<<4))) = o[n][r]*sigmoidf_(gv[n][r]);
    }
  }
  __syncthreads();
  #pragma unroll
  for (int it=0; it<8; ++it){
    int row = it*16 + rowg;
    float4 v = *(const float4*)(wlds + row*512 + ((c4<<2) ^ ((row&4)<<4)));
    *(float4*)(out + (size_t)(pos0+row)*CC + c4) = v;
  }
}

extern "C" void kernel_launch(void* const* d_in, const int* in_sizes, int n_in,
                              void* d_out, int out_size, void* d_ws, size_t ws_size,
                              hipStream_t stream){
  const float* z     = (const float*)d_in[0];
  const float* mask  = (const float*)d_in[1];
  const float* w_ap  = (const float*)d_in[2];
  const float* b_ap  = (const float*)d_in[3];
  const float* w_bp  = (const float*)d_in[4];
  const float* b_bp  = (const float*)d_in[5];
  const float* w_ag  = (const float*)d_in[6];
  const float* b_ag  = (const float*)d_in[7];
  const float* w_bg  = (const float*)d_in[8];
  const float* b_bg  = (const float*)d_in[9];
  const float* w_g   = (const float*)d_in[10];
  const float* b_g   = (const float*)d_in[11];
  const float* w_z   = (const float*)d_in[12];
  const float* b_z   = (const float*)d_in[13];
  const float* ln_in_w  = (const float*)d_in[14];
  const float* ln_in_b  = (const float*)d_in[15];
  const float* ln_out_w = (const float*)d_in[16];
  const float* ln_out_b = (const float*)d_in[17];

  unsigned short* wfrag = (unsigned short*)d_ws;   // 10 planes * 32KB = 320KB

  k0_wprep<<<80, 256, 0, stream>>>(w_ap, w_ag, w_bp, w_bg, w_g, w_z, wfrag);
  k_fused<<<NB, TPB, 0, stream>>>(z, mask, b_ap, b_ag, b_bp, b_bg, b_g, b_z,
                                  ln_in_w, ln_in_b, ln_out_w, ln_out_b,
                                  wfrag, (float*)d_out);
}

// Round 7
// 124.428 us; speedup vs baseline: 2.1185x; 1.5608x over previous
//
#include <hip/hip_runtime.h>

#define NN 384
#define CC 128
#define PP (NN*NN)      // 147456 positions
#define PB 64           // positions per block
#define NB (PP/PB)      // 2304 blocks
#define TPB 256         // 4 waves; each wave owns one 16-row stripe

typedef __attribute__((ext_vector_type(8))) short bf16x8;
typedef __attribute__((ext_vector_type(4))) float f32x4;
typedef __attribute__((ext_vector_type(8))) unsigned short u16x8;

// weight planes in wfrag, 16384 ushorts (32KB) each
#define PL_APH 0
#define PL_AGH 1
#define PL_BPH 2
#define PL_BGH 3
#define PL_APL 4
#define PL_AGL 5
#define PL_BPL 6
#define PL_BGL 7
#define PL_G   8
#define PL_Z   9

__device__ __forceinline__ unsigned short f2bf(float f){
  unsigned u = __float_as_uint(f);
  u += 0x7FFFu + ((u>>16)&1u);          // RNE
  return (unsigned short)(u>>16);
}
__device__ __forceinline__ float bf2f(unsigned h){
  return __uint_as_float(h<<16);
}
__device__ __forceinline__ unsigned pack2(float a, float b){
  return (unsigned)f2bf(a) | ((unsigned)f2bf(b)<<16);
}
__device__ __forceinline__ float sigmoidf_(float x){
  return __fdividef(1.0f, 1.0f + __expf(-x));
}

// ---------------------------------------------------------------------------
// K0: weights -> bf16 hi/lo planes in MFMA-B-fragment order.
// chunk (k0*8+n)*64+l holds W[n*16+(l&15)][k0*32+(l>>4)*8 .. +7].
// ---------------------------------------------------------------------------
__global__ __launch_bounds__(256) void k0_wprep(
    const float* __restrict__ wap, const float* __restrict__ wag,
    const float* __restrict__ wbp, const float* __restrict__ wbg,
    const float* __restrict__ wg,  const float* __restrict__ wz,
    unsigned short* __restrict__ wfrag){
  int tid = blockIdx.x*256 + threadIdx.x;      // 0..20479
  int plane = tid >> 11;                       // 0..9
  int chunk = tid & 2047;
  int mat = (plane < 8) ? (plane & 3) : (plane == 8 ? 4 : 5);
  bool lo = (plane >= 4) && (plane < 8);
  const float* W = (mat==0)?wap:(mat==1)?wag:(mat==2)?wbp:(mat==3)?wbg:(mat==4)?wg:wz;
  int k0 = chunk >> 9, n = (chunk >> 6) & 7, l = chunk & 63;
  int o  = n*16 + (l & 15);
  int kb = k0*32 + ((l>>4)<<3);
  const float* s = W + o*128 + kb;
  u16x8 v;
  #pragma unroll
  for (int e=0;e<8;e++){
    float w = s[e];
    unsigned short h = f2bf(w);
    v[e] = lo ? f2bf(w - bf2f(h)) : h;
  }
  *(u16x8*)(wfrag + (size_t)tid*8) = v;
}

// ---------------------------------------------------------------------------
// Stage one 32KB plane into the LDS slot. global_load_lds: zero staging VGPRs,
// dest = wave-uniform base + lane*16 (linear copy; plane layout is linear).
// ---------------------------------------------------------------------------
__device__ __forceinline__ void stage_plane(const unsigned short* __restrict__ g,
                                            unsigned char* slot, int t){
  int wv = t>>6, l = t&63;
#if defined(__has_builtin) && __has_builtin(__builtin_amdgcn_global_load_lds)
  const unsigned char* src = (const unsigned char*)g + wv*8192 + l*16;
  unsigned char* dst = slot + wv*8192;
  #pragma unroll
  for (int i=0;i<8;i++)
    __builtin_amdgcn_global_load_lds(
        (const __attribute__((address_space(1))) unsigned int*)(src + i*1024),
        (__attribute__((address_space(3))) unsigned int*)(dst + i*1024),
        16, 0, 0);
#else
  #pragma unroll
  for (int i=0;i<8;i++)
    *(uint4*)(slot + i*4096 + t*16) =
        *(const uint4*)((const unsigned char*)g + i*4096 + t*16);
#endif
}

// ---------------------------------------------------------------------------
// MFMA passes over one LDS-staged plane.
// A-frag: row=row0+(l&15), k=k0*32+(l>>4)*8+e. D: row=row0+(l>>4)*4+r, col=n*16+(l&15).
// ---------------------------------------------------------------------------
__device__ __forceinline__ void pass_HL(const bf16x8 aH[4], const bf16x8 aL[4],
    const unsigned char* w, int l, f32x4 acc[8]){
  #pragma unroll
  for (int k0=0;k0<4;k0++){
    #pragma unroll
    for (int n=0;n<8;n++){
      bf16x8 f = *(const bf16x8*)(w + ((k0*8+n)*64 + l)*16);
      acc[n] = __builtin_amdgcn_mfma_f32_16x16x32_bf16(aH[k0], f, acc[n], 0,0,0);
      acc[n] = __builtin_amdgcn_mfma_f32_16x16x32_bf16(aL[k0], f, acc[n], 0,0,0);
    }
  }
}

__device__ __forceinline__ void pass_H(const bf16x8 a[4],
    const unsigned char* w, int l, f32x4 acc[8]){
  #pragma unroll
  for (int k0=0;k0<4;k0++){
    #pragma unroll
    for (int n=0;n<8;n++){
      bf16x8 f = *(const bf16x8*)(w + ((k0*8+n)*64 + l)*16);
      acc[n] = __builtin_amdgcn_mfma_f32_16x16x32_bf16(a[k0], f, acc[n], 0,0,0);
    }
  }
}

__device__ __forceinline__ void bias_init(const float* __restrict__ b, int l, f32x4 acc[8]){
  #pragma unroll
  for (int n=0;n<8;n++){
    float v = b[n*16 + (l&15)];
    f32x4 iv = {v,v,v,v};
    acc[n]=iv;
  }
}

// ---------------------------------------------------------------------------
// Fused kernel, per 64-position tile; 4 waves, one 16-row stripe each.
// LDS 64KB: [0,32K) zn hi/lo (16K+16K) -> xa f32 -> xn bf16 / f32 repack
//           [32K,64K) weight plane slot.
// ---------------------------------------------------------------------------
__global__ __launch_bounds__(TPB,2) void k_fused(
    const float* __restrict__ z, const float* __restrict__ mask,
    const float* __restrict__ bap, const float* __restrict__ bag,
    const float* __restrict__ bbp, const float* __restrict__ bbg,
    const float* __restrict__ bgg, const float* __restrict__ bz,
    const float* __restrict__ lniw, const float* __restrict__ lnib,
    const float* __restrict__ lnow, const float* __restrict__ lnob,
    const unsigned short* __restrict__ wfrag,
    float* __restrict__ out){
  __shared__ unsigned char lds[65536];
  unsigned char* bufH  = lds;            // 16KB zn hi
  unsigned char* bufL  = lds + 16384;    // 16KB zn lo
  unsigned char* wslot = lds + 32768;    // 32KB plane slot
  const int t = threadIdx.x;
  const int pos0 = blockIdx.x * PB;
  const int rowg = t>>5, c4 = (t&31)<<2;

  // stage APH while P1 runs
  stage_plane(wfrag + PL_APH*16384, wslot, t);

  // ---- P1: LN(z), two-pass var, hi/lo split ----
  {
    float4 lw = *(const float4*)(lniw + c4);
    float4 lb = *(const float4*)(lnib + c4);
    #pragma unroll
    for (int it=0; it<8; ++it){
      int row = it*8 + rowg;
      float4 v = *(const float4*)(z + (size_t)(pos0+row)*CC + c4);
      float s = v.x+v.y+v.z+v.w;
      #pragma unroll
      for (int mm=1; mm<32; mm<<=1) s += __shfl_xor(s,mm);
      float mu = s*(1.0f/128.0f);
      float d0=v.x-mu, d1=v.y-mu, d2=v.z-mu, d3=v.w-mu;
      float ss = d0*d0+d1*d1+d2*d2+d3*d3;
      #pragma unroll
      for (int mm=1; mm<32; mm<<=1) ss += __shfl_xor(ss,mm);
      float rstd = rsqrtf(ss*(1.0f/128.0f) + 1e-5f);
      float n0=d0*rstd*lw.x+lb.x, n1=d1*rstd*lw.y+lb.y;
      float n2=d2*rstd*lw.z+lb.z, n3=d3*rstd*lw.w+lb.w;
      unsigned short h0=f2bf(n0), h1=f2bf(n1), h2=f2bf(n2), h3=f2bf(n3);
      unsigned off = (unsigned)(row*256 + ((c4<<1) ^ ((row&7)<<4)));
      *(uint2*)(bufH + off) = make_uint2((unsigned)h0|((unsigned)h1<<16),
                                         (unsigned)h2|((unsigned)h3<<16));
      *(uint2*)(bufL + off) = make_uint2(pack2(n0-bf2f(h0), n1-bf2f(h1)),
                                         pack2(n2-bf2f(h2), n3-bf2f(h3)));
    }
  }
  __syncthreads();

  const int wv = t>>6, l = t&63;
  const int cb = l&15;            // D col-within-16 / A row-within-16
  const int g4 = (l>>4)<<2;       // D row-quad base
  const int row0 = wv*16;         // this wave's stripe

  // ---- P2: A-fragments (hi and lo) of own stripe ----
  bf16x8 aH[4], aLo[4];
  #pragma unroll
  for (int k0=0;k0<4;k0++){
    int row = row0 + cb;
    unsigned off = (unsigned)(row*256 + ((((l>>4)<<4) + (k0<<6)) ^ ((row&7)<<4)));
    aH[k0]  = *(const bf16x8*)(bufH + off);
    aLo[k0] = *(const bf16x8*)(bufL + off);
  }

  float mk[4];
  #pragma unroll
  for (int r=0;r<4;r++) mk[r] = mask[pos0 + row0 + g4 + r];

  f32x4 accp[8], accg[8];

  // ---- P3: a (f32-grade, plane-sequential) ----
  bias_init(bap, l, accp);
  pass_HL(aH, aLo, wslot, l, accp);                       // APH
  __syncthreads();
  stage_plane(wfrag + PL_AGH*16384, wslot, t);
  __syncthreads();
  bias_init(bag, l, accg);
  pass_HL(aH, aLo, wslot, l, accg);                       // AGH
  __syncthreads();
  stage_plane(wfrag + PL_APL*16384, wslot, t);
  __syncthreads();
  pass_H(aH, wslot, l, accp);                             // APL
  __syncthreads();
  stage_plane(wfrag + PL_AGL*16384, wslot, t);
  __syncthreads();
  pass_H(aH, wslot, l, accg);                             // AGL
  // xa = accp*sig(accg)*mk -> LDS f32 (zn region dead; thread-own rows)
  #pragma unroll
  for (int n=0;n<8;n++){
    #pragma unroll
    for (int r=0;r<4;r++){
      int row = row0 + g4 + r;
      int col = n*16 + cb;
      float av = accp[n][r]*sigmoidf_(accg[n][r])*mk[r];
      *(float*)(lds + row*512 + ((col<<2) ^ ((row&4)<<4))) = av;
    }
  }
  __syncthreads();
  stage_plane(wfrag + PL_BPH*16384, wslot, t);
  __syncthreads();

  // ---- P4: b (plane-sequential); aLo dies after BGH ----
  bias_init(bbp, l, accp);
  pass_HL(aH, aLo, wslot, l, accp);                       // BPH
  __syncthreads();
  stage_plane(wfrag + PL_BGH*16384, wslot, t);
  __syncthreads();
  bias_init(bbg, l, accg);
  pass_HL(aH, aLo, wslot, l, accg);                       // BGH (last aLo use)
  __syncthreads();
  stage_plane(wfrag + PL_BPL*16384, wslot, t);
  __syncthreads();
  pass_H(aH, wslot, l, accp);                             // BPL
  __syncthreads();
  stage_plane(wfrag + PL_BGL*16384, wslot, t);
  __syncthreads();
  pass_H(aH, wslot, l, accg);                             // BGL

  // x = xa * b (read back own xa), then LN(x) in-register
  f32x4 xv[8];
  #pragma unroll
  for (int n=0;n<8;n++){
    #pragma unroll
    for (int r=0;r<4;r++){
      int row = row0 + g4 + r;
      int col = n*16 + cb;
      float xa = *(const float*)(lds + row*512 + ((col<<2) ^ ((row&4)<<4)));
      xv[n][r] = xa * (accp[n][r]*sigmoidf_(accg[n][r])*mk[r]);
    }
  }
  float lw8[8], lb8[8];
  #pragma unroll
  for (int n=0;n<8;n++){ lw8[n]=lnow[n*16+cb]; lb8[n]=lnob[n*16+cb]; }
  float mu_[4], rs_[4];
  #pragma unroll
  for (int r=0;r<4;r++){
    float s=0.f;
    #pragma unroll
    for (int n=0;n<8;n++) s += xv[n][r];
    #pragma unroll
    for (int mm=1; mm<16; mm<<=1) s += __shfl_xor(s,mm);
    float mu = s*(1.0f/128.0f);
    float ss=0.f;
    #pragma unroll
    for (int n=0;n<8;n++){ float d = xv[n][r]-mu; ss += d*d; }
    #pragma unroll
    for (int mm=1; mm<16; mm<<=1) ss += __shfl_xor(ss,mm);
    mu_[r] = mu;
    rs_[r] = rsqrtf(ss*(1.0f/128.0f) + 1e-5f);
  }
  __syncthreads();   // all xa reads + BGL wslot reads complete

  // xn bf16 -> lds base (row*256, swizzled); stage Z in parallel
  stage_plane(wfrag + PL_Z*16384, wslot, t);
  #pragma unroll
  for (int r=0;r<4;r++){
    int row = row0 + g4 + r;
    #pragma unroll
    for (int n=0;n<8;n++){
      int col = n*16 + cb;
      float v = (xv[n][r]-mu_[r])*rs_[r]*lw8[n]+lb8[n];
      *(unsigned short*)(lds + row*256 + ((col<<1) ^ ((row&7)<<4))) = f2bf(v);
    }
  }
  __syncthreads();

  // ---- P6: o = xn@Wz^T+bz ; gv = zn@Wg^T+bg ----
  bf16x8 a2[4];
  #pragma unroll
  for (int k0=0;k0<4;k0++){
    int row = row0 + cb;
    unsigned off = (unsigned)(row*256 + ((((l>>4)<<4) + (k0<<6)) ^ ((row&7)<<4)));
    a2[k0] = *(const bf16x8*)(lds + off);
  }
  f32x4 o[8], gv[8];
  bias_init(bz, l, o);
  pass_H(a2, wslot, l, o);                                // Z plane
  __syncthreads();
  stage_plane(wfrag + PL_G*16384, wslot, t);
  __syncthreads();
  bias_init(bgg, l, gv);
  pass_H(aH, wslot, l, gv);                               // G plane

  // ---- P7: f32 repack into lds[0,32K) (a2/xn long dead), then store ----
  #pragma unroll
  for (int r=0;r<4;r++){
    int row = row0 + g4 + r;
    #pragma unroll
    for (int n=0;n<8;n++){
      int col = n*16 + cb;
      *(float*)(lds + row*512 + ((col<<2) ^ ((row&4)<<4))) = o[n][r]*sigmoidf_(gv[n][r]);
    }
  }
  __syncthreads();
  #pragma unroll
  for (int it=0; it<8; ++it){
    int row = it*8 + rowg;
    float4 v = *(const float4*)(lds + row*512 + ((c4<<2) ^ ((row&4)<<4)));
    *(float4*)(out + (size_t)(pos0+row)*CC + c4) = v;
  }
}

extern "C" void kernel_launch(void* const* d_in, const int* in_sizes, int n_in,
                              void* d_out, int out_size, void* d_ws, size_t ws_size,
                              hipStream_t stream){
  const float* z     = (const float*)d_in[0];
  const float* mask  = (const float*)d_in[1];
  const float* w_ap  = (const float*)d_in[2];
  const float* b_ap  = (const float*)d_in[3];
  const float* w_bp  = (const float*)d_in[4];
  const float* b_bp  = (const float*)d_in[5];
  const float* w_ag  = (const float*)d_in[6];
  const float* b_ag  = (const float*)d_in[7];
  const float* w_bg  = (const float*)d_in[8];
  const float* b_bg  = (const float*)d_in[9];
  const float* w_g   = (const float*)d_in[10];
  const float* b_g   = (const float*)d_in[11];
  const float* w_z   = (const float*)d_in[12];
  const float* b_z   = (const float*)d_in[13];
  const float* ln_in_w  = (const float*)d_in[14];
  const float* ln_in_b  = (const float*)d_in[15];
  const float* ln_out_w = (const float*)d_in[16];
  const float* ln_out_b = (const float*)d_in[17];

  unsigned short* wfrag = (unsigned short*)d_ws;   // 10 planes * 32KB = 320KB

  k0_wprep<<<80, 256, 0, stream>>>(w_ap, w_ag, w_bp, w_bg, w_g, w_z, wfrag);
  k_fused<<<NB, TPB, 0, stream>>>(z, mask, b_ap, b_ag, b_bp, b_bg, b_g, b_z,
                                  ln_in_w, ln_in_b, ln_out_w, ln_out_b,
                                  wfrag, (float*)d_out);
}